// Round 2
// baseline (668.234 us; speedup 1.0000x reference)
//
#include <hip/hip_runtime.h>

// X (64, 512, 4000) fp32; D=10, STRIDE=10 -> w=400.
// out[b,n,k] = X[b,n,10k+9] / X[b,n,10k] - 2.0f
//
// R1 lesson: scalar loads at 80B lane stride = 64 unique lines per wave
// instruction -> request-rate bound at ~0.87 TB/s (666 us). Fix: stream X
// with perfectly coalesced float4 loads into LDS (contiguous copy), do the
// stride-20 gather from LDS, write coalesced float2.
//
// Block = 256 threads = one contiguous 5120-float slab (256 groups of 20).
// 4000 % 20 == 0 and total floats % 5120 == 0, so no row-crossing issues
// and no tail. LDS 20 KB -> 8 blocks/CU, full occupancy.
// LDS read gather has an 8-way bank conflict (stride 20 words, period 8
// mod 32) but its total cost (~20 us grid-wide) hides under ~92 us of HBM.

#define FLOATS_PER_BLOCK 5120  // 256 groups * 20 floats

__global__ __launch_bounds__(256) void ts_return_kernel(
    const float* __restrict__ X,
    float* __restrict__ out)
{
    __shared__ float s[FLOATS_PER_BLOCK];

    const int t = threadIdx.x;
    const size_t base = (size_t)blockIdx.x * FLOATS_PER_BLOCK;

    // Coalesced stream: 5 x (256 lanes x 16B) = 20KB contiguous
    const float4* __restrict__ Xv = reinterpret_cast<const float4*>(X + base);
    float4* sv = reinterpret_cast<float4*>(s);
#pragma unroll
    for (int i = 0; i < 5; ++i) {
        sv[i * 256 + t] = Xv[i * 256 + t];
    }
    __syncthreads();

    // Each thread owns one 20-float group -> 2 outputs
    const float x0  = s[20 * t + 0];
    const float x9  = s[20 * t + 9];
    const float x10 = s[20 * t + 10];
    const float x19 = s[20 * t + 19];

    float2 r;
    r.x = x9  / x0  - 2.0f;
    r.y = x19 / x10 - 2.0f;

    // out index = blockIdx*256 + t (float2 units) -> fully coalesced 8B stores
    reinterpret_cast<float2*>(out)[(size_t)blockIdx.x * 256 + t] = r;
}

extern "C" void kernel_launch(void* const* d_in, const int* in_sizes, int n_in,
                              void* d_out, int out_size, void* d_ws, size_t ws_size,
                              hipStream_t stream) {
    const float* X = (const float*)d_in[0];
    float* out = (float*)d_out;

    // total floats = 64*512*4000 = 131,072,000 = 25600 * 5120 (exact)
    int n_blocks = (in_sizes[0]) / FLOATS_PER_BLOCK;
    ts_return_kernel<<<n_blocks, 256, 0, stream>>>(X, out);
}